// Round 7
// baseline (568.648 us; speedup 1.0000x reference)
//
#include <hip/hip_runtime.h>
#include <hip/hip_bf16.h>

#define HW 3136
#define CIN 256
#define COUT 512
#define NBATCH 32
#define EPS 1e-5f
#define DW_TH 4.0f
#define PW_TH 1e-3f

typedef __attribute__((ext_vector_type(8))) short s16x8;
typedef __attribute__((ext_vector_type(4))) float f32x4;
typedef unsigned int u32;
typedef unsigned short u16;

__device__ __forceinline__ void async_copy16(void* lds, const void* g) {
    __builtin_amdgcn_global_load_lds((const __attribute__((address_space(1))) unsigned int*)g,
                                     (__attribute__((address_space(3))) unsigned int*)lds,
                                     16, 0, 0);
}

__device__ __forceinline__ u16 bf16_bits(float f) {
    __hip_bfloat16 h = __float2bfloat16(f);
    union { __hip_bfloat16 h; u16 u; } cv; cv.h = h; return cv.u;
}

// ---------------- dw v7: direct-streaming depthwise (no LDS staging, no barrier in data path) ----------------
// blocks 0..2047: block = (n, 4-channel group cq). thread = (c4 0..3, row r 0..55); 224 active.
//   Each thread streams rows r-1,r,r+1 of its channel from global (L1 serves halo reuse),
//   computes 56 px, writes NHWC y + per-(n,c) max via tiny block reduction. ~1KB LDS -> max occupancy.
// blocks 2048..2111: prep (W fp32->bf16, scale/shift fold)
__global__ __launch_bounds__(256) void dw_kernel(
    const float* __restrict__ x, const float* __restrict__ dww, const float* __restrict__ dwb,
    const float* __restrict__ g1, const float* __restrict__ b1,
    const float* __restrict__ m1, const float* __restrict__ v1,
    const float* __restrict__ pww, const float* __restrict__ pwb,
    const float* __restrict__ g2, const float* __restrict__ b2,
    const float* __restrict__ m2, const float* __restrict__ v2,
    u16* __restrict__ y, float* __restrict__ dwmaxp,
    u16* __restrict__ wb, float2* __restrict__ scsh)
{
    const int bid = blockIdx.x;
    const int t = threadIdx.x;

    if (bid >= 2048) {              // ---- prep path ----
        const int gid = (bid - 2048) * 256 + t;     // 0..16383
        const int base = gid * 8;                   // covers 131072 = COUT*CIN
        const float4 a = *(const float4*)(pww + base);
        const float4 b = *(const float4*)(pww + base + 4);
        union { u16 u[8]; s16x8 v; } pk;
        pk.u[0] = bf16_bits(a.x); pk.u[1] = bf16_bits(a.y);
        pk.u[2] = bf16_bits(a.z); pk.u[3] = bf16_bits(a.w);
        pk.u[4] = bf16_bits(b.x); pk.u[5] = bf16_bits(b.y);
        pk.u[6] = bf16_bits(b.z); pk.u[7] = bf16_bits(b.w);
        *(s16x8*)(wb + base) = pk.v;
        if (gid < COUT) {
            const float sc = g2[gid] * rsqrtf(v2[gid] + EPS);
            const float sh = fmaf(-m2[gid], sc, b2[gid]) + pwb[gid] * sc;
            scsh[gid] = make_float2(sc, sh);
        }
        return;
    }

    __shared__ float sm[256];

    const int n  = bid >> 6;            // batch
    const int cq = bid & 63;            // 4-channel group
    const int c4 = t / 56;              // 0..3 (4 = idle lanes 224..255)
    const int r  = t - c4 * 56;         // row 0..55
    const bool active = (c4 < 4);

    float vmax = 0.f;
    if (active) {
        const int ch = cq * 4 + c4;
        const float* wp = dww + ch * 9;
        // zero top/bottom row weights at image edges (pointers clamped in-bounds)
        const float km = (r > 0) ? 1.f : 0.f;
        const float kp = (r < 55) ? 1.f : 0.f;
        const float w00 = wp[0] * km, w01 = wp[1] * km, w02 = wp[2] * km;
        const float w10 = wp[3],      w11 = wp[4],      w12 = wp[5];
        const float w20 = wp[6] * kp, w21 = wp[7] * kp, w22 = wp[8] * kp;
        const float sc = g1[ch] * rsqrtf(v1[ch] + EPS);
        const float sh = fmaf(-m1[ch], sc, b1[ch]) + dwb[ch] * sc;

        const float* xb = x + (size_t)(n * CIN + ch) * HW;
        const float* rm = xb + (size_t)((r == 0)  ? 0  : r - 1) * 56;   // 16B-aligned (224B rows)
        const float* r0 = xb + (size_t)r * 56;
        const float* rp = xb + (size_t)((r == 55) ? 55 : r + 1) * 56;

        u16* yo = y + (size_t)(n * HW + r * 56) * CIN + ch;

        float4 cm = *(const float4*)rm;
        float4 c0 = *(const float4*)r0;
        float4 cp = *(const float4*)rp;
        float lm = 0.f, l0 = 0.f, lp = 0.f;

#pragma unroll
        for (int chk = 0; chk < 14; ++chk) {
            float4 nm, n0, np;
            if (chk < 13) {
                nm = *(const float4*)(rm + 4 * chk + 4);
                n0 = *(const float4*)(r0 + 4 * chk + 4);
                np = *(const float4*)(rp + 4 * chk + 4);
            } else {
                nm = n0 = np = make_float4(0.f, 0.f, 0.f, 0.f);
            }
            float s0 = w00*lm   + w01*cm.x + w02*cm.y
                     + w10*l0   + w11*c0.x + w12*c0.y
                     + w20*lp   + w21*cp.x + w22*cp.y;
            float s1 = w00*cm.x + w01*cm.y + w02*cm.z
                     + w10*c0.x + w11*c0.y + w12*c0.z
                     + w20*cp.x + w21*cp.y + w22*cp.z;
            float s2 = w00*cm.y + w01*cm.z + w02*cm.w
                     + w10*c0.y + w11*c0.z + w12*c0.w
                     + w20*cp.y + w21*cp.z + w22*cp.w;
            float s3 = w00*cm.z + w01*cm.w + w02*nm.x
                     + w10*c0.z + w11*c0.w + w12*n0.x
                     + w20*cp.z + w21*cp.w + w22*np.x;
            const float v0  = fmaxf(fmaf(s0, sc, sh), 0.f);
            const float v1s = fmaxf(fmaf(s1, sc, sh), 0.f);
            const float v2s = fmaxf(fmaf(s2, sc, sh), 0.f);
            const float v3  = fmaxf(fmaf(s3, sc, sh), 0.f);
            vmax = fmaxf(fmaxf(vmax, fmaxf(v0, v1s)), fmaxf(v2s, v3));
            yo[(4 * chk + 0) * CIN] = bf16_bits(v0);
            yo[(4 * chk + 1) * CIN] = bf16_bits(v1s);
            yo[(4 * chk + 2) * CIN] = bf16_bits(v2s);
            yo[(4 * chk + 3) * CIN] = bf16_bits(v3);
            lm = cm.w; l0 = c0.w; lp = cp.w;
            cm = nm; c0 = n0; cp = np;
        }
    }

    // per-(n,ch) max: block == (n, 4ch) exactly -> single-level reduce, plain store
    sm[t] = vmax;
    __syncthreads();
    if (t < 4) {
        float m = sm[t * 56];
#pragma unroll
        for (int k = 1; k < 56; ++k) m = fmaxf(m, sm[t * 56 + k]);
        dwmaxp[n * CIN + cq * 4 + t] = m;
    }
}

// ---------------- pw (R2-proven, verbatim): O=256 x HW=112, BK=32, 3-buffer counted vmcnt ----------------
// 4 waves x 64 O-rows; per wave per K-step: exactly 6 global_load_lds (4 W + 2 Y), 11 ds_read, 28 MFMA.
__global__ __launch_bounds__(256, 2) void pw_kernel(
    const u16* __restrict__ y, const u16* __restrict__ wb,
    const float2* __restrict__ scsh, const float* __restrict__ dwmaxp,
    float* __restrict__ out, float* __restrict__ omaxp)
{
    __shared__ __align__(16) u16 Wt[3][256 * 32];   // 48 KB: [o][k], pitch 64B
    __shared__ __align__(16) u16 Yt[3][128 * 32];   // 24 KB: [hw][k] (rows 112..127 pad for uniform vmcnt)
    __shared__ __align__(16) u16 msk[CIN];          // 0xFFFF keep / 0 cut per k

    // 1792 = 8 XCD x 224; per XCD: ot fastest within (n,hwt) -> Y tile L2 reuse
    const int bid = blockIdx.x;
    const int g   = (bid & 7) * 224 + (bid >> 3);
    const int ot  = g & 1;
    const int r2  = g >> 1;
    const int hwt = r2 % 28;
    const int n   = r2 / 28;

    const int t = threadIdx.x;
    const int w = t >> 6;          // wave 0..3
    const int l = t & 63;
    const int lo = l & 15, hi = l >> 4;

    const int o_blk  = ot * 256;
    const int hw_blk = n * HW + hwt * 112;

    const u16* wg = wb + (size_t)(o_blk + w * 64 + (l >> 2)) * CIN + (l & 3) * 8;
    const u16* yg = y  + (size_t)(hw_blk + (l >> 2)) * CIN + (l & 3) * 8;

    // dw channel-cut mask: single-level read
    msk[t] = (dwmaxp[n * CIN + t] >= DW_TH) ? (u16)0xFFFFu : (u16)0u;
    __syncthreads();    // msk visible to all waves; no pipeline loads issued yet

    f32x4 acc[4][7];
#pragma unroll
    for (int s = 0; s < 4; ++s)
#pragma unroll
        for (int j = 0; j < 7; ++j) acc[s][j] = (f32x4){0.f, 0.f, 0.f, 0.f};

    // per-wave stage of K-tile k0 into buffer buf: 4 W-loads + 2 Y-loads (Y group 7 dups group 6's src)
#define STAGE(buf, k0) do {                                                            \
        char* WtB_ = (char*)&Wt[buf][0];                                               \
        char* YtB_ = (char*)&Yt[buf][0];                                               \
        _Pragma("unroll")                                                              \
        for (int i_ = 0; i_ < 4; ++i_)                                                 \
            async_copy16(WtB_ + (w * 64 + i_ * 16) * 64 + l * 16,                      \
                         wg + (k0) + (size_t)(i_ * 16) * CIN);                         \
        const int j0_ = 2 * w;                                                         \
        async_copy16(YtB_ + (j0_ * 16) * 64 + l * 16,                                  \
                     yg + (k0) + (size_t)(j0_ * 16) * CIN);                            \
        const int j1_ = j0_ + 1, sj_ = (j1_ == 7) ? 6 : j1_;                           \
        async_copy16(YtB_ + (j1_ * 16) * 64 + l * 16,                                  \
                     yg + (k0) + (size_t)(sj_ * 16) * CIN);                            \
    } while (0)

    STAGE(0, 0);
    asm volatile("" ::: "memory");     // keep buf0's 6 loads older than buf1's in issue order
    STAGE(1, 32);

#pragma unroll
    for (int tk = 0; tk < 8; ++tk) {
        const int cur = tk % 3;
        // wait for this wave's K-tile tk loads (oldest 6); keep tk+1's 6 in flight
        if (tk < 7) asm volatile("s_waitcnt vmcnt(6)" ::: "memory");
        else        asm volatile("s_waitcnt vmcnt(0)" ::: "memory");
        __builtin_amdgcn_s_barrier();            // all waves' tile-tk loads landed; prev-step reads done
        __builtin_amdgcn_sched_barrier(0);       // no ds_read hoisting above the barrier
        if (tk < 6) { STAGE((tk + 2) % 3, (tk + 2) * 32); }   // overwrites buf read 2 steps ago

        const char* WtB = (const char*)&Wt[cur][0];
        const char* YtB = (const char*)&Yt[cur][0];
        const s16x8 m8 = *(const s16x8*)((const char*)msk + tk * 64 + hi * 16);

        s16x8 af[4], bf7[7];
#pragma unroll
        for (int s = 0; s < 4; ++s) {
            af[s] = *(const s16x8*)(WtB + (w * 64 + s * 16 + lo) * 64 + hi * 16);
            af[s] = af[s] & m8;    // zero cut channels (A-column zero == y-channel zero)
        }
#pragma unroll
        for (int j = 0; j < 7; ++j)
            bf7[j] = *(const s16x8*)(YtB + (j * 16 + lo) * 64 + hi * 16);

        __builtin_amdgcn_s_setprio(1);
#pragma unroll
        for (int s = 0; s < 4; ++s)
#pragma unroll
            for (int j = 0; j < 7; ++j)
                acc[s][j] = __builtin_amdgcn_mfma_f32_16x16x32_bf16(af[s], bf7[j], acc[s][j], 0, 0, 0);
        __builtin_amdgcn_s_setprio(0);
    }
#undef STAGE

    // epilogue: C/D layout col=lane&15 (hw), row=(lane>>4)*4+reg (o); partial max store (no atomics)
#pragma unroll
    for (int s = 0; s < 4; ++s) {
#pragma unroll
        for (int r = 0; r < 4; ++r) {
            const int o = o_blk + w * 64 + s * 16 + hi * 4 + r;
            const float2 ss = scsh[o];
            float m = 0.f;
            float* op = out + (size_t)(n * COUT + o) * HW + hwt * 112 + lo;
#pragma unroll
            for (int j = 0; j < 7; ++j) {
                const float v = fmaxf(fmaf(acc[s][j][r], ss.x, ss.y), 0.f);
                op[j * 16] = v;
                m = fmaxf(m, v);
            }
            m = fmaxf(m, __shfl_xor(m, 1));
            m = fmaxf(m, __shfl_xor(m, 2));
            m = fmaxf(m, __shfl_xor(m, 4));
            m = fmaxf(m, __shfl_xor(m, 8));
            if (lo == 0) omaxp[(size_t)(n * COUT + o) * 28 + hwt] = m;
        }
    }
}

// ---------------- pw channel cut: reduce 28 hw-tile partials, zero if below threshold ----------------
__global__ __launch_bounds__(64) void pwcut_kernel(const float* __restrict__ omaxp, float* __restrict__ out)
{
    const int b = blockIdx.x;   // n*COUT + o
    const int t = threadIdx.x;
    float m = (t < 28) ? omaxp[(size_t)b * 28 + t] : 0.f;
#pragma unroll
    for (int d = 1; d < 64; d <<= 1) m = fmaxf(m, __shfl_xor(m, d));   // full 64-lane reduce
    if (m >= PW_TH) return;
    float4* p = (float4*)(out + (size_t)b * HW);
    const float4 z = make_float4(0.f, 0.f, 0.f, 0.f);
    for (int i = t; i < HW / 4; i += 64) p[i] = z;
}

extern "C" void kernel_launch(void* const* d_in, const int* in_sizes, int n_in,
                              void* d_out, int out_size, void* d_ws, size_t ws_size,
                              hipStream_t stream) {
    const float* x   = (const float*)d_in[0];
    const float* dww = (const float*)d_in[1];
    const float* dwb = (const float*)d_in[2];
    const float* g1  = (const float*)d_in[3];
    const float* b1  = (const float*)d_in[4];
    const float* m1  = (const float*)d_in[5];
    const float* v1  = (const float*)d_in[6];
    const float* pww = (const float*)d_in[7];
    const float* pwb = (const float*)d_in[8];
    const float* g2  = (const float*)d_in[9];
    const float* b2  = (const float*)d_in[10];
    const float* m2  = (const float*)d_in[11];
    const float* v2  = (const float*)d_in[12];
    float* out = (float*)d_out;

    // ws layout (no zero-init required anywhere):
    // [0, 1.8M)  omaxp   (16384 * 28 f32 partial maxes)
    // [2M, +32K) dwmaxp  (32 * 256 f32 per-(n,c) maxes)
    // [3M, +4K)  scsh
    // [4M, +256K) W bf16
    // [8M, +51.4M) y NHWC bf16
    float*  omaxp  = (float*)d_ws;
    float*  dwmaxp = (float*)((char*)d_ws + (2 << 20));
    float2* scsh   = (float2*)((char*)d_ws + (3 << 20));
    u16*    wbf    = (u16*)((char*)d_ws + (4 << 20));
    u16*    yv     = (u16*)((char*)d_ws + (8 << 20));

    dw_kernel<<<2048 + 64, 256, 0, stream>>>(x, dww, dwb, g1, b1, m1, v1,
                                             pww, pwb, g2, b2, m2, v2,
                                             yv, dwmaxp, wbf, scsh);
    pw_kernel<<<1792, 256, 0, stream>>>(yv, wbf, scsh, dwmaxp, out, omaxp);
    pwcut_kernel<<<NBATCH * COUT, 64, 0, stream>>>(omaxp, out);
}